// Round 6
// baseline (485.846 us; speedup 1.0000x reference)
//
#include <hip/hip_runtime.h>
#include <stdint.h>

#define B_DIM 4
#define L_DIM 512
#define D_DIM 768
#define S_DIM 4096
#define DFF_DIM 3072
#define M_DIM (B_DIM * S_DIM)   // 16384

typedef unsigned short ushort_t;
typedef __attribute__((ext_vector_type(8))) short short8;
typedef __attribute__((ext_vector_type(4))) float floatx4;

// round-to-nearest-even fp32 -> bf16 bits
__device__ __forceinline__ ushort_t f2bf(float x) {
  unsigned int u = __float_as_uint(x);
  u += 0x7FFFu + ((u >> 16) & 1u);
  return (ushort_t)(u >> 16);
}

// async 16B global->LDS (wave-uniform base + lane*16 layout required)
__device__ __forceinline__ void load_lds16(const ushort_t* g, ushort_t* lds) {
  __builtin_amdgcn_global_load_lds(
      (const __attribute__((address_space(1))) unsigned int*)g,
      (__attribute__((address_space(3))) unsigned int*)lds, 16, 0, 0);
}

// ---------------------------------------------------------------------------
// Fused prep: W1 transpose | W2 transpose | span gather+mean, one launch.
// ---------------------------------------------------------------------------
__device__ __forceinline__ void transpose_body(const float* __restrict__ in,
                                               ushort_t* __restrict__ out,
                                               int K, int N, int kb, int nb) {
  __shared__ float tile[32][33];
  const int k0 = kb * 32;
  const int n0 = nb * 32;
  const int tx = threadIdx.x & 31;
  const int ty = threadIdx.x >> 5;  // 0..7
#pragma unroll
  for (int r = 0; r < 32; r += 8)
    tile[ty + r][tx] = in[(long)(k0 + ty + r) * N + n0 + tx];
  __syncthreads();
#pragma unroll
  for (int r = 0; r < 32; r += 8)
    out[(long)(n0 + ty + r) * K + k0 + tx] = f2bf(tile[tx][ty + r]);
}

__device__ __forceinline__ void span_body(const float* __restrict__ h,
                                          const int* __restrict__ span_idx,
                                          ushort_t* __restrict__ A, int blk) {
  const int wave = threadIdx.x >> 6;
  const int lane = threadIdx.x & 63;
  const int span = blk * 4 + wave;  // 0..M-1
  const int b = span >> 12;         // span / S_DIM
  const int start = span_idx[span * 2 + 0];
  const int end   = span_idx[span * 2 + 1];
  const float inv = 1.0f / (float)(end - start + 1);
  const float* hb = h + ((long)b * L_DIM + start) * D_DIM + lane;
  float a[12];
#pragma unroll
  for (int c = 0; c < 12; ++c) a[c] = 0.0f;
  for (int p = start; p <= end; ++p) {
#pragma unroll
    for (int c = 0; c < 12; ++c) a[c] += hb[c * 64];
    hb += D_DIM;
  }
  ushort_t* o = A + (long)span * D_DIM + lane;
#pragma unroll
  for (int c = 0; c < 12; ++c) o[c * 64] = f2bf(a[c] * inv);
}

__global__ __launch_bounds__(256)
void prep(const float* __restrict__ W1, ushort_t* __restrict__ W1T,
          const float* __restrict__ W2, ushort_t* __restrict__ W2T,
          const float* __restrict__ h, const int* __restrict__ span_idx,
          ushort_t* __restrict__ A) {
  const int blk = blockIdx.x;
  if (blk < 2304) {
    transpose_body(W1, W1T, D_DIM, DFF_DIM, blk % 24, blk / 24);
  } else if (blk < 4608) {
    const int b = blk - 2304;
    transpose_body(W2, W2T, DFF_DIM, D_DIM, b % 96, b / 96);
  } else {
    span_body(h, span_idx, A, blk - 4608);
  }
}

// ---------------------------------------------------------------------------
// bf16 GEMM: C[M][N] = A[M][K] * Bt[N][K]^T (+bias epilogue)
// 128x128 tile, BK=32, 4 waves each computing 64x64 via 4x4 of 16x16x32.
//
// A operand: global_load_lds DMA into double-buffered LDS (16 KB total),
//            one barrier per iteration. Segment s covers LDS element s*8
//            (s1 = tid+256 -> element tid*8 + 2048  <-- R5 bug was +4096).
// B operand: DIRECT global->register (16 contiguous bytes at
//            Bt[n][k0+quad*8] = natural global_load_dwordx4, L2-resident),
//            register double-buffered; loads for iter k+1 issue right after
//            barrier k so they land behind a full iteration of compute.
// Halves LDS-pipe traffic (the measured #1 consumer) and moves B onto the
// near-idle VMEM/L2 pipe. k-loop unrolled x2 for compile-time buffer parity.
// MODE 0: out = relu(acc + bias[col]) -> bf16   (GEMM1 -> Hmid)
// MODE 1: out = acc + bias[col]       -> fp32   (GEMM2 -> final)
// ---------------------------------------------------------------------------
template <int MODE>
__global__ __launch_bounds__(256)
void gemm_bt(const ushort_t* __restrict__ A, const ushort_t* __restrict__ Bt,
             const float* __restrict__ bias, void* __restrict__ Cv,
             int M, int N, int K) {
  __shared__ ushort_t As[2][128 * 32];

  const int tid  = threadIdx.x;
  const int lane = tid & 63;
  const int wave = tid >> 6;
  const int l16  = lane & 15;
  const int quad = lane >> 4;

  const int bm = blockIdx.x;
  const int bn = blockIdx.y;

  const int wm = (wave & 1) * 64;
  const int wn = (wave >> 1) * 64;

  floatx4 acc[4][4];
#pragma unroll
  for (int i = 0; i < 4; ++i)
#pragma unroll
    for (int j = 0; j < 4; ++j)
      acc[i][j] = (floatx4)0.0f;

  // A staging: 512 16-B segments per tile; seg s -> row s>>2, chunk s&3.
  // Thread t covers s0=t (rows 0..63) and s1=t+256 (rows 64..127).
  const int s0 = tid;
  const ushort_t* gA0 = A + (long)(bm * 128 + (s0 >> 2)) * K + (s0 & 3) * 8;
  const long a1off = (long)64 * K;  // +64 rows, same chunk

  // B fragment pointer for this lane (j adds j*16*K, k adds k0)
  const ushort_t* gB = Bt + (long)(bn * 128 + wn + l16) * K + quad * 8;
  const long jstride = (long)16 * K;  // uniform

  const int nk = K >> 5;  // K/32 iterations (even: 24 or 96)

  short8 b0[4], b1[4];  // B register double buffer

  // prologue: A tile 0 -> LDS buf 0; B frags for iter 0 -> b0
  load_lds16(gA0, &As[0][0] + s0 * 8);
  load_lds16(gA0 + a1off, &As[0][0] + s0 * 8 + 2048);
#pragma unroll
  for (int j = 0; j < 4; ++j)
    b0[j] = *(const short8*)(gB + j * jstride);

  for (int kk = 0; kk < nk; kk += 2) {
    // ---- even step: cur = buffers 0, next = buffers 1 ----
    __syncthreads();  // drains A DMA (tile kk) + B loads (iter kk)
    {
      const int off = (kk + 1) * 32;  // kk+1 < nk always (nk even)
      load_lds16(gA0 + off, &As[1][0] + s0 * 8);
      load_lds16(gA0 + a1off + off, &As[1][0] + s0 * 8 + 2048);
#pragma unroll
      for (int j = 0; j < 4; ++j)
        b1[j] = *(const short8*)(gB + j * jstride + off);
    }
    {
      short8 af[4];
#pragma unroll
      for (int i = 0; i < 4; ++i)
        af[i] = *(const short8*)(&As[0][0] + (wm + i * 16 + l16) * 32 + quad * 8);
#pragma unroll
      for (int i = 0; i < 4; ++i)
#pragma unroll
        for (int j = 0; j < 4; ++j)
          acc[i][j] = __builtin_amdgcn_mfma_f32_16x16x32_bf16(af[i], b0[j], acc[i][j], 0, 0, 0);
    }

    // ---- odd step: cur = buffers 1, next = buffers 0 ----
    __syncthreads();  // drains A DMA (tile kk+1) + B loads (iter kk+1)
    if (kk + 2 < nk) {
      const int off = (kk + 2) * 32;
      load_lds16(gA0 + off, &As[0][0] + s0 * 8);
      load_lds16(gA0 + a1off + off, &As[0][0] + s0 * 8 + 2048);
#pragma unroll
      for (int j = 0; j < 4; ++j)
        b0[j] = *(const short8*)(gB + j * jstride + off);
    }
    {
      short8 af[4];
#pragma unroll
      for (int i = 0; i < 4; ++i)
        af[i] = *(const short8*)(&As[1][0] + (wm + i * 16 + l16) * 32 + quad * 8);
#pragma unroll
      for (int i = 0; i < 4; ++i)
#pragma unroll
        for (int j = 0; j < 4; ++j)
          acc[i][j] = __builtin_amdgcn_mfma_f32_16x16x32_bf16(af[i], b1[j], acc[i][j], 0, 0, 0);
    }
  }

  // epilogue: C/D layout col = lane&15, row = quad*4 + r
#pragma unroll
  for (int i = 0; i < 4; ++i) {
#pragma unroll
    for (int j = 0; j < 4; ++j) {
      const int col = bn * 128 + wn + j * 16 + l16;
      const float bv = bias[col];
      const int row0 = bm * 128 + wm + i * 16 + quad * 4;
#pragma unroll
      for (int r = 0; r < 4; ++r) {
        float v = acc[i][j][r] + bv;
        if (MODE == 0) {
          v = v > 0.0f ? v : 0.0f;
          ((ushort_t*)Cv)[(long)(row0 + r) * N + col] = f2bf(v);
        } else {
          ((float*)Cv)[(long)(row0 + r) * N + col] = v;
        }
      }
    }
  }
}

extern "C" void kernel_launch(void* const* d_in, const int* in_sizes, int n_in,
                              void* d_out, int out_size, void* d_ws, size_t ws_size,
                              hipStream_t stream) {
  const float* h        = (const float*)d_in[0];
  const int*   span_idx = (const int*)d_in[1];
  const float* W1       = (const float*)d_in[2];
  const float* b1       = (const float*)d_in[3];
  const float* W2       = (const float*)d_in[4];
  const float* b2       = (const float*)d_in[5];
  float* out = (float*)d_out;

  // workspace layout (bf16 elements): A | W1T | W2T | Hmid
  ushort_t* A   = (ushort_t*)d_ws;
  ushort_t* W1T = A + (size_t)M_DIM * D_DIM;
  ushort_t* W2T = W1T + (size_t)DFF_DIM * D_DIM;
  ushort_t* Hm  = W2T + (size_t)D_DIM * DFF_DIM;

  // fused prep: both weight transposes + span gather in one launch
  prep<<<2304 + 2304 + M_DIM / 4, 256, 0, stream>>>(W1, W1T, W2, W2T, h, span_idx, A);

  // GEMM1: A (M x D) * W1 (D x DFF) + b1, relu -> Hmid bf16 (M x DFF)
  gemm_bt<0><<<dim3(M_DIM / 128, DFF_DIM / 128), 256, 0, stream>>>(
      A, W1T, b1, Hm, M_DIM, DFF_DIM, D_DIM);

  // GEMM2: Hmid (M x DFF) * W2 (DFF x D) + b2 -> out fp32 (M x D)
  gemm_bt<1><<<dim3(M_DIM / 128, D_DIM / 128), 256, 0, stream>>>(
      Hm, W2T, b2, out, M_DIM, D_DIM, DFF_DIM);
}

// Round 7
// 312.809 us; speedup vs baseline: 1.5532x; 1.5532x over previous
//
#include <hip/hip_runtime.h>
#include <stdint.h>

#define B_DIM 4
#define L_DIM 512
#define D_DIM 768
#define S_DIM 4096
#define DFF_DIM 3072
#define M_DIM (B_DIM * S_DIM)   // 16384

typedef unsigned short ushort_t;
typedef __attribute__((ext_vector_type(8))) short short8;
typedef __attribute__((ext_vector_type(4))) float floatx4;

// round-to-nearest-even fp32 -> bf16 bits
__device__ __forceinline__ ushort_t f2bf(float x) {
  unsigned int u = __float_as_uint(x);
  u += 0x7FFFu + ((u >> 16) & 1u);
  return (ushort_t)(u >> 16);
}

// async 16B global->LDS (wave-uniform base + lane*16 layout required)
__device__ __forceinline__ void load_lds16(const ushort_t* g, ushort_t* lds) {
  __builtin_amdgcn_global_load_lds(
      (const __attribute__((address_space(1))) unsigned int*)g,
      (__attribute__((address_space(3))) unsigned int*)lds, 16, 0, 0);
}

// ---------------------------------------------------------------------------
// Fused prep: W1 transpose | W2 transpose | span gather+mean, one launch.
// ---------------------------------------------------------------------------
__device__ __forceinline__ void transpose_body(const float* __restrict__ in,
                                               ushort_t* __restrict__ out,
                                               int K, int N, int kb, int nb) {
  __shared__ float tile[32][33];
  const int k0 = kb * 32;
  const int n0 = nb * 32;
  const int tx = threadIdx.x & 31;
  const int ty = threadIdx.x >> 5;  // 0..7
#pragma unroll
  for (int r = 0; r < 32; r += 8)
    tile[ty + r][tx] = in[(long)(k0 + ty + r) * N + n0 + tx];
  __syncthreads();
#pragma unroll
  for (int r = 0; r < 32; r += 8)
    out[(long)(n0 + ty + r) * K + k0 + tx] = f2bf(tile[tx][ty + r]);
}

__device__ __forceinline__ void span_body(const float* __restrict__ h,
                                          const int* __restrict__ span_idx,
                                          ushort_t* __restrict__ A, int blk) {
  const int wave = threadIdx.x >> 6;
  const int lane = threadIdx.x & 63;
  const int span = blk * 4 + wave;  // 0..M-1
  const int b = span >> 12;         // span / S_DIM
  const int start = span_idx[span * 2 + 0];
  const int end   = span_idx[span * 2 + 1];
  const float inv = 1.0f / (float)(end - start + 1);
  const float* hb = h + ((long)b * L_DIM + start) * D_DIM + lane;
  float a[12];
#pragma unroll
  for (int c = 0; c < 12; ++c) a[c] = 0.0f;
  for (int p = start; p <= end; ++p) {
#pragma unroll
    for (int c = 0; c < 12; ++c) a[c] += hb[c * 64];
    hb += D_DIM;
  }
  ushort_t* o = A + (long)span * D_DIM + lane;
#pragma unroll
  for (int c = 0; c < 12; ++c) o[c * 64] = f2bf(a[c] * inv);
}

__global__ __launch_bounds__(256)
void prep(const float* __restrict__ W1, ushort_t* __restrict__ W1T,
          const float* __restrict__ W2, ushort_t* __restrict__ W2T,
          const float* __restrict__ h, const int* __restrict__ span_idx,
          ushort_t* __restrict__ A) {
  const int blk = blockIdx.x;
  if (blk < 2304) {
    transpose_body(W1, W1T, D_DIM, DFF_DIM, blk % 24, blk / 24);
  } else if (blk < 4608) {
    const int b = blk - 2304;
    transpose_body(W2, W2T, DFF_DIM, D_DIM, b % 96, b / 96);
  } else {
    span_body(h, span_idx, A, blk - 4608);
  }
}

// ---------------------------------------------------------------------------
// bf16 GEMM: C[M][N] = A[M][K] * Bt[N][K]^T (+bias epilogue)
// BM x 128 tile, BK=32, T = 2*BM threads (BM=128: 4 waves; BM=256: 8 waves),
// each wave computes a 64x64 sub-tile via 4x4 of mfma 16x16x32.
// Both operands staged via global_load_lds DMA, double-buffered LDS, one
// barrier per iteration (prefetch k+1 after barrier k, compute k).
// BM=256 raises resident waves/CU 10 -> 24 (3 blocks x 8 waves at 48 KB LDS)
// to fill latency holes; per-wave LDS traffic per FLOP is unchanged.
// MODE 0: out = relu(acc + bias[col]) -> bf16   (GEMM1 -> Hmid)
// MODE 1: out = acc + bias[col]       -> fp32   (GEMM2 -> final)
// ---------------------------------------------------------------------------
template <int MODE, int BM>
__global__ __launch_bounds__(BM * 2)
void gemm_bt(const ushort_t* __restrict__ A, const ushort_t* __restrict__ Bt,
             const float* __restrict__ bias, void* __restrict__ Cv,
             int M, int N, int K) {
  constexpr int T   = BM * 2;     // threads per block
  constexpr int WMW = BM / 64;    // waves along M (2 or 4)
  __shared__ ushort_t As[2][BM * 32];
  __shared__ ushort_t Bs[2][128 * 32];

  const int tid  = threadIdx.x;
  const int lane = tid & 63;
  const int wave = tid >> 6;
  const int l16  = lane & 15;
  const int quad = lane >> 4;

  const int bm = blockIdx.x;
  const int bn = blockIdx.y;

  const int wm = (wave % WMW) * 64;
  const int wn = (wave / WMW) * 64;

  floatx4 acc[4][4];
#pragma unroll
  for (int i = 0; i < 4; ++i)
#pragma unroll
    for (int j = 0; j < 4; ++j)
      acc[i][j] = (floatx4)0.0f;

  // A staging: BM*4 16-B segments per tile; seg s -> row s>>2, chunk s&3.
  // Thread t covers segs t (rows 0..T/4-1) and t+T (rows T/4..BM-1).
  // LDS elem offset of seg s is s*8 (second seg: +T*8).
  const ushort_t* gA0 = A + (long)(bm * BM + (tid >> 2)) * K + (tid & 3) * 8;
  const long a1off = (long)(T / 4) * K;  // +T/4 rows, same chunk
  // B staging: 512 segments. T==512: one per thread; T==256: two per thread.
  const ushort_t* gB0 = Bt + (long)(bn * 128 + (tid >> 2)) * K + (tid & 3) * 8;
  const long b1off = (long)64 * K;  // only used when T==256

  const int nk = K >> 5;  // K/32 iterations (24 or 96; even)

  // prologue: tile 0 -> buffers 0
  load_lds16(gA0, &As[0][0] + tid * 8);
  load_lds16(gA0 + a1off, &As[0][0] + tid * 8 + T * 8);
  load_lds16(gB0, &Bs[0][0] + tid * 8);
  if (T == 256) load_lds16(gB0 + b1off, &Bs[0][0] + tid * 8 + 2048);

  for (int kk = 0; kk < nk; kk += 2) {
    // ---- even step: cur = buffer 0, next = buffer 1 ----
    __syncthreads();  // drains DMA of tile kk
    {
      const int off = (kk + 1) * 32;  // kk+1 < nk (nk even)
      load_lds16(gA0 + off, &As[1][0] + tid * 8);
      load_lds16(gA0 + a1off + off, &As[1][0] + tid * 8 + T * 8);
      load_lds16(gB0 + off, &Bs[1][0] + tid * 8);
      if (T == 256) load_lds16(gB0 + b1off + off, &Bs[1][0] + tid * 8 + 2048);
    }
    {
      short8 af[4], bf[4];
#pragma unroll
      for (int i = 0; i < 4; ++i)
        af[i] = *(const short8*)(&As[0][0] + (wm + i * 16 + l16) * 32 + quad * 8);
#pragma unroll
      for (int j = 0; j < 4; ++j)
        bf[j] = *(const short8*)(&Bs[0][0] + (wn + j * 16 + l16) * 32 + quad * 8);
#pragma unroll
      for (int i = 0; i < 4; ++i)
#pragma unroll
        for (int j = 0; j < 4; ++j)
          acc[i][j] = __builtin_amdgcn_mfma_f32_16x16x32_bf16(af[i], bf[j], acc[i][j], 0, 0, 0);
    }

    // ---- odd step: cur = buffer 1, next = buffer 0 ----
    __syncthreads();  // drains DMA of tile kk+1
    if (kk + 2 < nk) {
      const int off = (kk + 2) * 32;
      load_lds16(gA0 + off, &As[0][0] + tid * 8);
      load_lds16(gA0 + a1off + off, &As[0][0] + tid * 8 + T * 8);
      load_lds16(gB0 + off, &Bs[0][0] + tid * 8);
      if (T == 256) load_lds16(gB0 + b1off + off, &Bs[0][0] + tid * 8 + 2048);
    }
    {
      short8 af[4], bf[4];
#pragma unroll
      for (int i = 0; i < 4; ++i)
        af[i] = *(const short8*)(&As[1][0] + (wm + i * 16 + l16) * 32 + quad * 8);
#pragma unroll
      for (int j = 0; j < 4; ++j)
        bf[j] = *(const short8*)(&Bs[1][0] + (wn + j * 16 + l16) * 32 + quad * 8);
#pragma unroll
      for (int i = 0; i < 4; ++i)
#pragma unroll
        for (int j = 0; j < 4; ++j)
          acc[i][j] = __builtin_amdgcn_mfma_f32_16x16x32_bf16(af[i], bf[j], acc[i][j], 0, 0, 0);
    }
  }

  // epilogue: C/D layout col = lane&15, row = quad*4 + r
#pragma unroll
  for (int i = 0; i < 4; ++i) {
#pragma unroll
    for (int j = 0; j < 4; ++j) {
      const int col = bn * 128 + wn + j * 16 + l16;
      const float bv = bias[col];
      const int row0 = bm * BM + wm + i * 16 + quad * 4;
#pragma unroll
      for (int r = 0; r < 4; ++r) {
        float v = acc[i][j][r] + bv;
        if (MODE == 0) {
          v = v > 0.0f ? v : 0.0f;
          ((ushort_t*)Cv)[(long)(row0 + r) * N + col] = f2bf(v);
        } else {
          ((float*)Cv)[(long)(row0 + r) * N + col] = v;
        }
      }
    }
  }
}

extern "C" void kernel_launch(void* const* d_in, const int* in_sizes, int n_in,
                              void* d_out, int out_size, void* d_ws, size_t ws_size,
                              hipStream_t stream) {
  const float* h        = (const float*)d_in[0];
  const int*   span_idx = (const int*)d_in[1];
  const float* W1       = (const float*)d_in[2];
  const float* b1       = (const float*)d_in[3];
  const float* W2       = (const float*)d_in[4];
  const float* b2       = (const float*)d_in[5];
  float* out = (float*)d_out;

  // workspace layout (bf16 elements): A | W1T | W2T | Hmid
  ushort_t* A   = (ushort_t*)d_ws;
  ushort_t* W1T = A + (size_t)M_DIM * D_DIM;
  ushort_t* W2T = W1T + (size_t)DFF_DIM * D_DIM;
  ushort_t* Hm  = W2T + (size_t)D_DIM * DFF_DIM;

  // fused prep: both weight transposes + span gather in one launch
  prep<<<2304 + 2304 + M_DIM / 4, 256, 0, stream>>>(W1, W1T, W2, W2T, h, span_idx, A);

  // GEMM1: A (M x D) * W1 (D x DFF) + b1, relu -> Hmid bf16 (M x DFF)
  // 256x128 tile, 512 threads: 64 x 24 = 1536 blocks, 3 blocks/CU resident.
  gemm_bt<0, 256><<<dim3(M_DIM / 256, DFF_DIM / 128), 512, 0, stream>>>(
      A, W1T, b1, Hm, M_DIM, DFF_DIM, D_DIM);

  // GEMM2: Hmid (M x DFF) * W2 (DFF x D) + b2 -> out fp32 (M x D)
  // 128x128 tile, 256 threads: 128 x 6 = 768 blocks (exactly 3/CU).
  gemm_bt<1, 128><<<dim3(M_DIM / 128, D_DIM / 128), 256, 0, stream>>>(
      Hm, W2T, b2, out, M_DIM, D_DIM, DFF_DIM);
}